// Round 5
// baseline (705.476 us; speedup 1.0000x reference)
//
#include <hip/hip_runtime.h>
#include <hip/hip_bf16.h>
#include <stdint.h>

#define N_OBS 65536
#define N_DIM 256
#define N_FUN 16
#define N_APP 8
#define MT 64
#define STRIDE 66560          // N_OBS + N_FUN*MT
#define MAXT 1040             // STRIDE/64
#define N_BLK 256

typedef __attribute__((ext_vector_type(8))) short v8s;
typedef __attribute__((ext_vector_type(4))) short v4s;
typedef __attribute__((ext_vector_type(4))) float v4f;

__device__ __forceinline__ unsigned short f2bf(float f) {
  union { float f; uint32_t u; } v;
  v.f = f;
  uint32_t u = v.u;
  return (unsigned short)((u + 0x7FFFu + ((u >> 16) & 1u)) >> 16);
}

// bijective XCD swizzle (grid % 8 == 0): consecutive work -> same XCD L2
__device__ __forceinline__ int xcd_swz(int bid, int n) {
  int q = n >> 3;
  return (bid & 7) * q + (bid >> 3);
}

__global__ void k_init(int* __restrict__ perm, int total) {
  int tid = blockIdx.x * 256 + threadIdx.x;
  if (tid < total) perm[tid] = -1;
}

// W (f,d,e) f32 -> Wt (f,e,d) bf16  (n-major, k contiguous)
__global__ void k_prep_w(const float* __restrict__ W, unsigned short* __restrict__ Wt) {
  int tid = blockIdx.x * 256 + threadIdx.x;
  int f = tid >> 16, n = (tid >> 8) & 255, k = tid & 255;
  Wt[tid] = f2bf(W[(f << 16) | (k << 8) | n]);
}

// per-block histogram: blockCnt[bin*N_BLK + block], bin = t*16+f (128 bins)
__global__ void k_hist(const int* __restrict__ fidx, int* __restrict__ blockCnt) {
  __shared__ int h[N_APP * N_FUN];
  int tid = threadIdx.x;
  if (tid < N_APP * N_FUN) h[tid] = 0;
  __syncthreads();
  size_t o = blockIdx.x * 256 + tid;
  const int4* p = (const int4*)(fidx + o * 8);
  int4 a = p[0], b = p[1];
  atomicAdd(&h[0 * N_FUN + a.x], 1);
  atomicAdd(&h[1 * N_FUN + a.y], 1);
  atomicAdd(&h[2 * N_FUN + a.z], 1);
  atomicAdd(&h[3 * N_FUN + a.w], 1);
  atomicAdd(&h[4 * N_FUN + b.x], 1);
  atomicAdd(&h[5 * N_FUN + b.y], 1);
  atomicAdd(&h[6 * N_FUN + b.z], 1);
  atomicAdd(&h[7 * N_FUN + b.w], 1);
  __syncthreads();
  if (tid < N_APP * N_FUN) blockCnt[tid * N_BLK + blockIdx.x] = h[tid];
}

// tot[bin] = sum over blocks (128 blocks, parallel tree reduce)
__global__ void k_tot(const int* __restrict__ blockCnt, int* __restrict__ tot) {
  __shared__ int s[256];
  int tid = threadIdx.x;
  s[tid] = blockCnt[blockIdx.x * N_BLK + tid];
  __syncthreads();
  for (int o = 128; o > 0; o >>= 1) {
    if (tid < o) s[tid] += s[tid + o];
    __syncthreads();
  }
  if (tid == 0) tot[blockIdx.x] = s[0];
}

// padded group bases pb[t*17+f] + tile->f map
__global__ void k_base(const int* __restrict__ tot, int* __restrict__ pb,
                       int* __restrict__ tilef) {
  __shared__ int pbl[N_APP * 17];
  int tid = threadIdx.x;
  if (tid < N_APP) {
    int base = 0;
    for (int f = 0; f < N_FUN; ++f) {
      pbl[tid * 17 + f] = base;
      int c = tot[tid * N_FUN + f];
      base += (c + MT - 1) & ~(MT - 1);
    }
    pbl[tid * 17 + 16] = base;
  }
  __syncthreads();
  if (tid < N_APP * 17) pb[tid] = pbl[tid];
  for (int idx = tid; idx < N_APP * MAXT; idx += 256) {
    int t = idx / MAXT, q = idx - t * MAXT;
    int posn = q * MT;
    int fg = 0;
    #pragma unroll
    for (int f = 1; f < N_FUN; ++f)
      if (posn >= pbl[t * 17 + f]) fg = f;
    tilef[idx] = fg;
  }
}

// blockOff[bin*N_BLK + b] = pb-base + exclusive prefix of block counts
__global__ void k_off(const int* __restrict__ blockCnt, const int* __restrict__ pb,
                      int* __restrict__ blockOff) {
  __shared__ int s[256];
  int bin = blockIdx.x, tid = threadIdx.x;
  int c = blockCnt[bin * N_BLK + tid];
  s[tid] = c;
  __syncthreads();
  for (int o = 1; o < 256; o <<= 1) {
    int v = (tid >= o) ? s[tid - o] : 0;
    __syncthreads();
    s[tid] += v;
    __syncthreads();
  }
  int t = bin >> 4, f = bin & 15;
  blockOff[bin * N_BLK + tid] = pb[t * 17 + f] + s[tid] - c;
}

// scatter row ids via per-block LDS cursors
__global__ void k_scatter(const int* __restrict__ fidx, const int* __restrict__ blockOff,
                          int* __restrict__ perm) {
  __shared__ int cur[N_APP * N_FUN];
  int tid = threadIdx.x;
  if (tid < N_APP * N_FUN) cur[tid] = blockOff[tid * N_BLK + blockIdx.x];
  __syncthreads();
  size_t o = blockIdx.x * 256 + tid;
  const int4* p = (const int4*)(fidx + o * 8);
  int4 a = p[0], b = p[1];
  int fs[8] = {a.x, a.y, a.z, a.w, b.x, b.y, b.z, b.w};
  #pragma unroll
  for (int t = 0; t < N_APP; ++t) {
    int pos = atomicAdd(&cur[t * N_FUN + fs[t]], 1);
    perm[t * STRIDE + pos] = (int)o;
  }
}

// pos_t[o] = slot of row o in layout t (t=1..7)
__global__ void k_pos(const int* __restrict__ perm, int* __restrict__ pos) {
  int tid = blockIdx.x * 256 + threadIdx.x;
  if (tid >= 7 * STRIDE) return;
  int t = tid / STRIDE + 1, s = tid - (t - 1) * STRIDE;
  int o = perm[t * STRIDE + s];
  if (o >= 0) pos[(t - 1) * N_OBS + o] = s;
}

// outpos[t][s] = pos_{t+1}[perm[t][s]] (t=0..6); in-place for t>=1
__global__ void k_outpos(int* __restrict__ perm, const int* __restrict__ pos,
                         int* __restrict__ outpos0) {
  int tid = blockIdx.x * 256 + threadIdx.x;
  if (tid >= 7 * STRIDE) return;
  int t = tid / STRIDE, s = tid - t * STRIDE;
  int o = perm[t * STRIDE + s];
  int val = (o >= 0) ? pos[t * N_OBS + o] : -1;
  if (t == 0) outpos0[s] = val;
  else perm[t * STRIDE + s] = val;
}

// ---- barrier-free, LDS-free step: one wave = 16 rows x 128 cols ----
// A-frag in regs (8 x v8s: row=lane&15, k=kk*32+(lane>>4)*8), B streamed from L2.
template <int SRC_F32, int DST_F32>
__global__ __launch_bounds__(256, 4)
void k_step(const void* __restrict__ src_, void* __restrict__ dst_,
            const unsigned short* __restrict__ Wt, const float* __restrict__ bias,
            const int* __restrict__ pb_t, const int* __restrict__ tilef_t,
            const int* __restrict__ outpos_t, const int* __restrict__ perm0) {
  int tid = threadIdx.x;
  int bid = xcd_swz(blockIdx.x, gridDim.x);
  int gw = bid * 4 + (tid >> 6);
  int rg = gw >> 1, half = gw & 1;
  if (rg * 16 >= pb_t[16]) return;
  int lane = tid & 63, l15 = lane & 15, lq = lane >> 4;
  int tile = rg >> 2;
  int f = tilef_t[tile];
  int myrow = rg * 16 + l15;

  v8s a[8];
  if (SRC_F32) {
    int grow = perm0[myrow];
    if (grow < 0) grow = 0;   // clamp; output masked at store
    const float* xr = (const float*)src_ + ((size_t)grow << 8) + (lq << 3);
    #pragma unroll
    for (int kk = 0; kk < 8; ++kk) {
      v4f v0 = *(const v4f*)(xr + kk * 32);
      v4f v1 = *(const v4f*)(xr + kk * 32 + 4);
      v8s t;
      t[0] = (short)f2bf(v0[0]); t[1] = (short)f2bf(v0[1]);
      t[2] = (short)f2bf(v0[2]); t[3] = (short)f2bf(v0[3]);
      t[4] = (short)f2bf(v1[0]); t[5] = (short)f2bf(v1[1]);
      t[6] = (short)f2bf(v1[2]); t[7] = (short)f2bf(v1[3]);
      a[kk] = t;
    }
  } else {
    const unsigned short* sr = (const unsigned short*)src_ + ((size_t)myrow << 8) + (lq << 3);
    #pragma unroll
    for (int kk = 0; kk < 8; ++kk)
      a[kk] = *(const v8s*)(sr + kk * 32);
  }

  v4f acc[8] = {};
  // B-frag base: row n = half*128 + nt*16 + l15, k = kk*32 + lq*8
  const unsigned short* Wf =
      Wt + ((size_t)f << 16) + ((size_t)((half << 7) + l15) << 8) + (lq << 3);
  #pragma unroll
  for (int kk = 0; kk < 8; ++kk) {
    #pragma unroll
    for (int nt = 0; nt < 8; ++nt) {
      v8s bfr = *(const v8s*)(Wf + (nt << 12) + (kk << 5));
      // swapped operands: D col(lane&15)=row m, D row(lq*4+r)=col n
      acc[nt] = __builtin_amdgcn_mfma_f32_16x16x32_bf16(bfr, a[kk], acc[nt], 0, 0, 0);
    }
  }

  int op = outpos_t[myrow];
  if (op < 0) return;
  const float* bf_ = bias + (f << 8) + (half << 7) + (lq << 2);
  if (DST_F32) {
    float* dr = (float*)dst_ + ((size_t)op << 8) + (half << 7) + (lq << 2);
    #pragma unroll
    for (int nt = 0; nt < 8; ++nt) {
      v4f bv = *(const v4f*)(bf_ + (nt << 4));
      v4f o = acc[nt] + bv;
      *(v4f*)(dr + (nt << 4)) = o;
    }
  } else {
    unsigned short* dr = (unsigned short*)dst_ + ((size_t)op << 8) + (half << 7) + (lq << 2);
    #pragma unroll
    for (int nt = 0; nt < 8; ++nt) {
      v4f bv = *(const v4f*)(bf_ + (nt << 4));
      v4s pk;
      pk[0] = (short)f2bf(acc[nt][0] + bv[0]);
      pk[1] = (short)f2bf(acc[nt][1] + bv[1]);
      pk[2] = (short)f2bf(acc[nt][2] + bv[2]);
      pk[3] = (short)f2bf(acc[nt][3] + bv[3]);
      *(v4s*)(dr + (nt << 4)) = pk;
    }
  }
}

extern "C" void kernel_launch(void* const* d_in, const int* in_sizes, int n_in,
                              void* d_out, int out_size, void* d_ws, size_t ws_size,
                              hipStream_t stream) {
  const float* x = (const float*)d_in[0];
  const int* fidx = (const int*)d_in[1];
  const float* W = (const float*)d_in[2];
  const float* bias = (const float*)d_in[3];
  char* ws = (char*)d_ws;

  // carryA: STRIDE rows x 512B = 34,078,720 B
  unsigned short* carryA = (unsigned short*)ws;
  // overlap carryA (all dead before step 0 writes it):
  int* blockCnt = (int*)ws;                        // 128*256*4 = 131072
  int* blockOff = (int*)(ws + 131072);             // 131072
  int* tot      = (int*)(ws + 262144);             // 512
  int* pos      = (int*)(ws + 262656);             // 7*65536*4 = 1,835,008
  unsigned short* Wt = (unsigned short*)(ws + 34078720);   // 2 MB
  int* perm    = (int*)(ws + 36175872);            // 8*66560*4 = 2,129,920
  int* pb      = (int*)(ws + 38305792);            // 544
  int* tilef   = (int*)(ws + 38306336);            // 33,280
  int* outpos0 = (int*)(ws + 38339616);            // 266,240 (end ~38.6 MB)
  unsigned short* carryB = (unsigned short*)d_out; // bf16 scratch (34 MB of 64)

  k_init<<<(N_APP * STRIDE + 255) / 256, 256, 0, stream>>>(perm, N_APP * STRIDE);
  k_prep_w<<<(N_FUN * 65536) / 256, 256, 0, stream>>>(W, Wt);
  k_hist<<<N_BLK, 256, 0, stream>>>(fidx, blockCnt);
  k_tot<<<128, 256, 0, stream>>>(blockCnt, tot);
  k_base<<<1, 256, 0, stream>>>(tot, pb, tilef);
  k_off<<<128, 256, 0, stream>>>(blockCnt, pb, blockOff);
  k_scatter<<<N_BLK, 256, 0, stream>>>(fidx, blockOff, perm);
  k_pos<<<(7 * STRIDE + 255) / 256, 256, 0, stream>>>(perm, pos);
  k_outpos<<<(7 * STRIDE + 255) / 256, 256, 0, stream>>>(perm, pos, outpos0);

  const int GS = 2080;   // ceil(66560/16/2 waves /4 per block); 2080 % 8 == 0
  // step 0: gather x(f32) -> carryA (layout-1 slots)
  k_step<1, 0><<<GS, 256, 0, stream>>>(x, carryA, Wt, bias, pb, tilef, outpos0, perm);
  // steps 1..6: contiguous bf16 -> next-layout slots (outpos in perm[t])
  for (int t = 1; t < 7; ++t) {
    const unsigned short* s = (t & 1) ? carryA : carryB;
    unsigned short* d = (t & 1) ? carryB : carryA;
    k_step<0, 0><<<GS, 256, 0, stream>>>(
        s, d, Wt, bias, pb + t * 17, tilef + t * MAXT, perm + t * STRIDE, nullptr);
  }
  // step 7: contiguous bf16 -> d_out f32 at original rows (perm[7] = row ids)
  k_step<0, 1><<<GS, 256, 0, stream>>>(
      carryA, d_out, Wt, bias, pb + 7 * 17, tilef + 7 * MAXT, perm + 7 * STRIDE, nullptr);
}

// Round 6
// 433.194 us; speedup vs baseline: 1.6285x; 1.6285x over previous
//
#include <hip/hip_runtime.h>
#include <hip/hip_bf16.h>
#include <stdint.h>

#define N_OBS 65536
#define N_DIM 256
#define N_FUN 16
#define N_APP 8
#define MT 64
#define STRIDE 66560          // N_OBS + N_FUN*MT
#define MAXT 1040             // STRIDE/64
#define N_BLK 256

typedef __attribute__((ext_vector_type(8))) short v8s;
typedef __attribute__((ext_vector_type(4))) short v4s;
typedef __attribute__((ext_vector_type(4))) float v4f;

__device__ __forceinline__ unsigned short f2bf(float f) {
  union { float f; uint32_t u; } v;
  v.f = f;
  uint32_t u = v.u;
  return (unsigned short)((u + 0x7FFFu + ((u >> 16) & 1u)) >> 16);
}

// bijective XCD swizzle (grid % 8 == 0): consecutive work -> same XCD L2
__device__ __forceinline__ int xcd_swz(int bid, int n) {
  int q = n >> 3;
  return (bid & 7) * q + (bid >> 3);
}

__global__ void k_init(int* __restrict__ perm, int total) {
  int tid = blockIdx.x * 256 + threadIdx.x;
  if (tid < total) perm[tid] = -1;
}

// W (f,d,e) f32 -> Wt (f,e,d) bf16  (n-major, k contiguous)
__global__ void k_prep_w(const float* __restrict__ W, unsigned short* __restrict__ Wt) {
  int tid = blockIdx.x * 256 + threadIdx.x;
  int f = tid >> 16, n = (tid >> 8) & 255, k = tid & 255;
  Wt[tid] = f2bf(W[(f << 16) | (k << 8) | n]);
}

// per-block histogram: blockCnt[bin*N_BLK + block], bin = t*16+f (128 bins)
__global__ void k_hist(const int* __restrict__ fidx, int* __restrict__ blockCnt) {
  __shared__ int h[N_APP * N_FUN];
  int tid = threadIdx.x;
  if (tid < N_APP * N_FUN) h[tid] = 0;
  __syncthreads();
  size_t o = blockIdx.x * 256 + tid;
  const int4* p = (const int4*)(fidx + o * 8);
  int4 a = p[0], b = p[1];
  atomicAdd(&h[0 * N_FUN + a.x], 1);
  atomicAdd(&h[1 * N_FUN + a.y], 1);
  atomicAdd(&h[2 * N_FUN + a.z], 1);
  atomicAdd(&h[3 * N_FUN + a.w], 1);
  atomicAdd(&h[4 * N_FUN + b.x], 1);
  atomicAdd(&h[5 * N_FUN + b.y], 1);
  atomicAdd(&h[6 * N_FUN + b.z], 1);
  atomicAdd(&h[7 * N_FUN + b.w], 1);
  __syncthreads();
  if (tid < N_APP * N_FUN) blockCnt[tid * N_BLK + blockIdx.x] = h[tid];
}

// tot[bin] = sum over blocks (128 blocks, parallel tree reduce)
__global__ void k_tot(const int* __restrict__ blockCnt, int* __restrict__ tot) {
  __shared__ int s[256];
  int tid = threadIdx.x;
  s[tid] = blockCnt[blockIdx.x * N_BLK + tid];
  __syncthreads();
  for (int o = 128; o > 0; o >>= 1) {
    if (tid < o) s[tid] += s[tid + o];
    __syncthreads();
  }
  if (tid == 0) tot[blockIdx.x] = s[0];
}

// padded group bases pb[t*17+f] + tile->f map
__global__ void k_base(const int* __restrict__ tot, int* __restrict__ pb,
                       int* __restrict__ tilef) {
  __shared__ int pbl[N_APP * 17];
  int tid = threadIdx.x;
  if (tid < N_APP) {
    int base = 0;
    for (int f = 0; f < N_FUN; ++f) {
      pbl[tid * 17 + f] = base;
      int c = tot[tid * N_FUN + f];
      base += (c + MT - 1) & ~(MT - 1);
    }
    pbl[tid * 17 + 16] = base;
  }
  __syncthreads();
  if (tid < N_APP * 17) pb[tid] = pbl[tid];
  for (int idx = tid; idx < N_APP * MAXT; idx += 256) {
    int t = idx / MAXT, q = idx - t * MAXT;
    int posn = q * MT;
    int fg = 0;
    #pragma unroll
    for (int f = 1; f < N_FUN; ++f)
      if (posn >= pbl[t * 17 + f]) fg = f;
    tilef[idx] = fg;
  }
}

// blockOff[bin*N_BLK + b] = pb-base + exclusive prefix of block counts
__global__ void k_off(const int* __restrict__ blockCnt, const int* __restrict__ pb,
                      int* __restrict__ blockOff) {
  __shared__ int s[256];
  int bin = blockIdx.x, tid = threadIdx.x;
  int c = blockCnt[bin * N_BLK + tid];
  s[tid] = c;
  __syncthreads();
  for (int o = 1; o < 256; o <<= 1) {
    int v = (tid >= o) ? s[tid - o] : 0;
    __syncthreads();
    s[tid] += v;
    __syncthreads();
  }
  int t = bin >> 4, f = bin & 15;
  blockOff[bin * N_BLK + tid] = pb[t * 17 + f] + s[tid] - c;
}

// scatter row ids via per-block LDS cursors
__global__ void k_scatter(const int* __restrict__ fidx, const int* __restrict__ blockOff,
                          int* __restrict__ perm) {
  __shared__ int cur[N_APP * N_FUN];
  int tid = threadIdx.x;
  if (tid < N_APP * N_FUN) cur[tid] = blockOff[tid * N_BLK + blockIdx.x];
  __syncthreads();
  size_t o = blockIdx.x * 256 + tid;
  const int4* p = (const int4*)(fidx + o * 8);
  int4 a = p[0], b = p[1];
  int fs[8] = {a.x, a.y, a.z, a.w, b.x, b.y, b.z, b.w};
  #pragma unroll
  for (int t = 0; t < N_APP; ++t) {
    int pos = atomicAdd(&cur[t * N_FUN + fs[t]], 1);
    perm[t * STRIDE + pos] = (int)o;
  }
}

// pos_t[o] = slot of row o in layout t (t=1..7)
__global__ void k_pos(const int* __restrict__ perm, int* __restrict__ pos) {
  int tid = blockIdx.x * 256 + threadIdx.x;
  if (tid >= 7 * STRIDE) return;
  int t = tid / STRIDE + 1, s = tid - (t - 1) * STRIDE;
  int o = perm[t * STRIDE + s];
  if (o >= 0) pos[(t - 1) * N_OBS + o] = s;
}

// outpos[t][s] = pos_{t+1}[perm[t][s]] (t=0..6); in-place for t>=1
__global__ void k_outpos(int* __restrict__ perm, const int* __restrict__ pos,
                         int* __restrict__ outpos0) {
  int tid = blockIdx.x * 256 + threadIdx.x;
  if (tid >= 7 * STRIDE) return;
  int t = tid / STRIDE, s = tid - t * STRIDE;
  int o = perm[t * STRIDE + s];
  int val = (o >= 0) ? pos[t * N_OBS + o] : -1;
  if (t == 0) outpos0[s] = val;
  else perm[t * STRIDE + s] = val;
}

// ---- W-in-registers step: block = 64-row tile; wave = 64-col slice ----
// B panel (64 cols x 256 k = 32 v8s = 128 VGPR) preloaded once per block;
// then 4 groups of 16 rows: contiguous A read -> 32 MFMA -> store. No LDS,
// no barriers.
template <int SRC_F32, int DST_F32>
__global__ __launch_bounds__(256, 2)
void k_step(const void* __restrict__ src_, void* __restrict__ dst_,
            const unsigned short* __restrict__ Wt, const float* __restrict__ bias,
            const int* __restrict__ pb_t, const int* __restrict__ tilef_t,
            const int* __restrict__ outpos_t, const int* __restrict__ perm0) {
  int tid = threadIdx.x;
  int tile = xcd_swz(blockIdx.x, gridDim.x);
  if (tile * MT >= pb_t[16]) return;
  int f = tilef_t[tile];
  int lane = tid & 63, wave = tid >> 6, l15 = lane & 15, lq = lane >> 4;
  int cb = wave << 6;                 // this wave's column base
  int rowbase = tile * MT;

  // B panel: frag (nt,kk) = 8 bf16 at row n=cb+nt*16+l15, k=kk*32+lq*8
  const unsigned short* Wf =
      Wt + ((size_t)f << 16) + ((size_t)(cb + l15) << 8) + (lq << 3);
  v8s b[4][8];
  #pragma unroll
  for (int nt = 0; nt < 4; ++nt)
    #pragma unroll
    for (int kk = 0; kk < 8; ++kk)
      b[nt][kk] = *(const v8s*)(Wf + (nt << 12) + (kk << 5));

  // bias for my 16 cols per nt: cols cb + nt*16 + lq*4 .. +3
  v4f bv[4];
  #pragma unroll
  for (int nt = 0; nt < 4; ++nt)
    bv[nt] = *(const v4f*)(bias + (f << 8) + cb + (nt << 4) + (lq << 2));

  #pragma unroll
  for (int g = 0; g < 4; ++g) {
    int mrow = rowbase + (g << 4) + l15;
    v8s a[8];
    if (SRC_F32) {
      int grow = perm0[mrow];
      if (grow < 0) grow = 0;   // clamp; output masked at store
      const float* xr = (const float*)src_ + ((size_t)grow << 8) + (lq << 3);
      #pragma unroll
      for (int kk = 0; kk < 8; ++kk) {
        v4f v0 = *(const v4f*)(xr + kk * 32);
        v4f v1 = *(const v4f*)(xr + kk * 32 + 4);
        v8s t;
        t[0] = (short)f2bf(v0[0]); t[1] = (short)f2bf(v0[1]);
        t[2] = (short)f2bf(v0[2]); t[3] = (short)f2bf(v0[3]);
        t[4] = (short)f2bf(v1[0]); t[5] = (short)f2bf(v1[1]);
        t[6] = (short)f2bf(v1[2]); t[7] = (short)f2bf(v1[3]);
        a[kk] = t;
      }
    } else {
      const unsigned short* sr =
          (const unsigned short*)src_ + ((size_t)mrow << 8) + (lq << 3);
      #pragma unroll
      for (int kk = 0; kk < 8; ++kk)
        a[kk] = *(const v8s*)(sr + kk * 32);
    }

    v4f acc[4] = {};
    #pragma unroll
    for (int kk = 0; kk < 8; ++kk) {
      #pragma unroll
      for (int nt = 0; nt < 4; ++nt)
        // swapped operands: D lane(l15)=row m, reg(lq*4+r)=col offset
        acc[nt] = __builtin_amdgcn_mfma_f32_16x16x32_bf16(b[nt][kk], a[kk], acc[nt], 0, 0, 0);
    }

    int op = outpos_t[mrow];
    if (op >= 0) {
      if (DST_F32) {
        float* dr = (float*)dst_ + ((size_t)op << 8) + cb + (lq << 2);
        #pragma unroll
        for (int nt = 0; nt < 4; ++nt) {
          v4f o = acc[nt] + bv[nt];
          *(v4f*)(dr + (nt << 4)) = o;
        }
      } else {
        unsigned short* dr = (unsigned short*)dst_ + ((size_t)op << 8) + cb + (lq << 2);
        #pragma unroll
        for (int nt = 0; nt < 4; ++nt) {
          v4s pk;
          pk[0] = (short)f2bf(acc[nt][0] + bv[nt][0]);
          pk[1] = (short)f2bf(acc[nt][1] + bv[nt][1]);
          pk[2] = (short)f2bf(acc[nt][2] + bv[nt][2]);
          pk[3] = (short)f2bf(acc[nt][3] + bv[nt][3]);
          *(v4s*)(dr + (nt << 4)) = pk;
        }
      }
    }
  }
}

extern "C" void kernel_launch(void* const* d_in, const int* in_sizes, int n_in,
                              void* d_out, int out_size, void* d_ws, size_t ws_size,
                              hipStream_t stream) {
  const float* x = (const float*)d_in[0];
  const int* fidx = (const int*)d_in[1];
  const float* W = (const float*)d_in[2];
  const float* bias = (const float*)d_in[3];
  char* ws = (char*)d_ws;

  // carryA: STRIDE rows x 512B = 34,078,720 B
  unsigned short* carryA = (unsigned short*)ws;
  // overlap carryA (all dead before step 0 writes it):
  int* blockCnt = (int*)ws;                        // 131072
  int* blockOff = (int*)(ws + 131072);             // 131072
  int* tot      = (int*)(ws + 262144);             // 512
  int* pos      = (int*)(ws + 262656);             // 1,835,008
  unsigned short* Wt = (unsigned short*)(ws + 34078720);   // 2 MB
  int* perm    = (int*)(ws + 36175872);            // 2,129,920
  int* pb      = (int*)(ws + 38305792);            // 544
  int* tilef   = (int*)(ws + 38306336);            // 33,280
  int* outpos0 = (int*)(ws + 38339616);            // 266,240 (end ~38.6 MB)
  unsigned short* carryB = (unsigned short*)d_out; // bf16 scratch (34 MB of 64)

  k_init<<<(N_APP * STRIDE + 255) / 256, 256, 0, stream>>>(perm, N_APP * STRIDE);
  k_prep_w<<<(N_FUN * 65536) / 256, 256, 0, stream>>>(W, Wt);
  k_hist<<<N_BLK, 256, 0, stream>>>(fidx, blockCnt);
  k_tot<<<128, 256, 0, stream>>>(blockCnt, tot);
  k_base<<<1, 256, 0, stream>>>(tot, pb, tilef);
  k_off<<<128, 256, 0, stream>>>(blockCnt, pb, blockOff);
  k_scatter<<<N_BLK, 256, 0, stream>>>(fidx, blockOff, perm);
  k_pos<<<(7 * STRIDE + 255) / 256, 256, 0, stream>>>(perm, pos);
  k_outpos<<<(7 * STRIDE + 255) / 256, 256, 0, stream>>>(perm, pos, outpos0);

  // step 0: gather x(f32) -> carryA (layout-1 slots)
  k_step<1, 0><<<MAXT, 256, 0, stream>>>(x, carryA, Wt, bias, pb, tilef, outpos0, perm);
  // steps 1..6: contiguous bf16 -> next-layout slots (outpos in perm[t])
  for (int t = 1; t < 7; ++t) {
    const unsigned short* s = (t & 1) ? carryA : carryB;
    unsigned short* d = (t & 1) ? carryB : carryA;
    k_step<0, 0><<<MAXT, 256, 0, stream>>>(
        s, d, Wt, bias, pb + t * 17, tilef + t * MAXT, perm + t * STRIDE, nullptr);
  }
  // step 7: contiguous bf16 -> d_out f32 at original rows (perm[7] = row ids)
  k_step<0, 1><<<MAXT, 256, 0, stream>>>(
      carryA, d_out, Wt, bias, pb + 7 * 17, tilef + 7 * MAXT, perm + 7 * STRIDE, nullptr);
}